// Round 3
// baseline (185.406 us; speedup 1.0000x reference)
//
#include <hip/hip_runtime.h>
#include <stdint.h>

#define MARGIN 0.3f

constexpr int N = 8192;
constexpr int D = 512;
constexpr int BM = 128, BN = 128, BK = 32;
constexpr int NT = N / BM;                    // 64 tiles per side
constexpr int NPAIR = NT * (NT + 1) / 2;      // 2080 unordered tile pairs
constexpr int NXCD = 8;
constexpr int WEDGE = NPAIR / NXCD;           // 260 pairs per XCD wedge

typedef short bf16x8 __attribute__((ext_vector_type(8)));
typedef float f32x4 __attribute__((ext_vector_type(4)));

// monotone float<->ordered-int encoding (for atomicMin/Max on float values)
__device__ __forceinline__ int enc_f32(float f) {
  int b = __float_as_int(f);
  return b >= 0 ? b : (b ^ 0x7fffffff);
}
__device__ __forceinline__ float dec_f32(int k) {
  return __int_as_float(k >= 0 ? k : (k ^ 0x7fffffff));
}

__device__ __forceinline__ unsigned short f2bf(float f) {
  unsigned u = __float_as_uint(f);
  u += 0x7fffu + ((u >> 16) & 1u); // RNE
  return (unsigned short)(u >> 16);
}

__device__ __forceinline__ void load_lds16(const unsigned short* g, short* l) {
  __builtin_amdgcn_global_load_lds((const __attribute__((address_space(1))) void*)g,
                                   (__attribute__((address_space(3))) void*)l,
                                   16, 0, 0);
}

// Decode pair index q (super-tile-major enumeration of the lower triangle)
// into (ti, tj), ti >= tj. Super-tile = 8x8 tiles; super-row SI holds
// 64*SI + 36 pairs; cumulative base(SI) = 32*SI^2 + 4*SI.
__device__ __forceinline__ void pair_from_q(int q, int& ti, int& tj) {
  int SI = 0;
  while (32 * (SI + 1) * (SI + 1) + 4 * (SI + 1) <= q) ++SI;
  int r = q - (32 * SI * SI + 4 * SI);
  int i, j, SJ;
  if (r < 64 * SI) {          // off-diagonal super: full 8x8, row-major
    SJ = r >> 6;
    int w = r & 63;
    i = w >> 3;
    j = w & 7;
  } else {                    // diagonal super: triangular 36 pairs
    int d = r - 64 * SI;
    SJ = SI;
    i = 0;
    while ((i + 1) * (i + 2) / 2 <= d) ++i;
    j = d - i * (i + 1) / 2;
  }
  ti = SI * 8 + i;
  tj = SJ * 8 + j;
}

// ---- kernel 1: L2-normalize rows -> bf16; init min/max arrays ----
__global__ __launch_bounds__(256) void normalize_rows(
    const float* __restrict__ emb, unsigned short* __restrict__ e,
    int* __restrict__ minpos_enc, int* __restrict__ maxneg_enc) {
  const int wave = threadIdx.x >> 6, lane = threadIdx.x & 63;
  const int row = blockIdx.x * 4 + wave;
  const float4* src = (const float4*)(emb + (size_t)row * D);
  float4 x0 = src[lane];
  float4 x1 = src[lane + 64];
  float ss = x0.x * x0.x + x0.y * x0.y + x0.z * x0.z + x0.w * x0.w +
             x1.x * x1.x + x1.y * x1.y + x1.z * x1.z + x1.w * x1.w;
#pragma unroll
  for (int m = 1; m < 64; m <<= 1) ss += __shfl_xor(ss, m, 64);
  float r = rsqrtf(ss);
  ushort4 o0 = {f2bf(x0.x * r), f2bf(x0.y * r), f2bf(x0.z * r), f2bf(x0.w * r)};
  ushort4 o1 = {f2bf(x1.x * r), f2bf(x1.y * r), f2bf(x1.z * r), f2bf(x1.w * r)};
  ushort4* dst = (ushort4*)(e + (size_t)row * D);
  dst[lane] = o0;
  dst[lane + 64] = o1;
  if (lane == 0) {
    minpos_enc[row] = 0x7f800000;      // enc(+inf)
    maxneg_enc[row] = (int)0x807fffff; // enc(-inf)
  }
}

// ---- kernel 2: symmetric fused Gram-tile GEMM + batch-hard mining ----
// 2080 blocks; block b -> pair q = 260*(b%8) + b/8 so each XCD (round-robin
// b%8) walks a contiguous run of the super-tile-ordered triangle (L2 local).
__global__ __launch_bounds__(256) void bh_gemm_sym(
    const unsigned short* __restrict__ e, const int* __restrict__ labels,
    int* __restrict__ minpos_enc, int* __restrict__ maxneg_enc) {
  __shared__ short As[BM * BK]; // [row][slot], slot = seg ^ ((row>>1)&3)
  __shared__ short Bs[BN * BK];

  const int b = blockIdx.x;
  const int q = WEDGE * (b & 7) + (b >> 3);
  int ti, tj;
  pair_from_q(q, ti, tj);
  const int iBase = ti * BM, jBase = tj * BN;
  const bool diag = (ti == tj);

  const int tid = threadIdx.x;
  const int lane = tid & 63;
  const int wave = tid >> 6;
  const int wr = wave >> 1, wc = wave & 1;
  const int quad = lane >> 4, n16 = lane & 15;

  f32x4 acc[4][4];
#pragma unroll
  for (int r = 0; r < 4; ++r)
#pragma unroll
    for (int c = 0; c < 4; ++c) acc[r][c] = (f32x4)0.0f;

  for (int k0 = 0; k0 < D; k0 += BK) {
    __syncthreads(); // previous chunk's reads done before overwrite
#pragma unroll
    for (int it = 0; it < 2; ++it) {
      int qq = it * 256 + tid; // LDS 16B-slot id; dest = uniform base + lane*16
      int row = qq >> 2, pos = qq & 3;
      int seg = pos ^ ((row >> 1) & 3); // bank-swizzle via global source addr
      load_lds16(e + (size_t)(iBase + row) * D + k0 + seg * 8, As + qq * 8);
      load_lds16(e + (size_t)(jBase + row) * D + k0 + seg * 8, Bs + qq * 8);
    }
    __syncthreads(); // drains vmcnt, staging visible

    bf16x8 af[4], bf[4];
#pragma unroll
    for (int r = 0; r < 4; ++r) {
      int rowa = wr * 64 + r * 16 + n16;
      af[r] = *(const bf16x8*)(As + rowa * BK + (quad ^ ((rowa >> 1) & 3)) * 8);
    }
#pragma unroll
    for (int c = 0; c < 4; ++c) {
      int rowb = wc * 64 + c * 16 + n16;
      bf[c] = *(const bf16x8*)(Bs + rowb * BK + (quad ^ ((rowb >> 1) & 3)) * 8);
    }
#pragma unroll
    for (int r = 0; r < 4; ++r)
#pragma unroll
      for (int c = 0; c < 4; ++c)
        acc[r][c] = __builtin_amdgcn_mfma_f32_16x16x32_bf16(af[r], bf[c], acc[r][c], 0, 0, 0);
  }

  // ---- epilogue: batch-hard mining, rows (and cols if off-diagonal) ----
  // C/D layout: row = wr*64 + r*16 + quad*4 + v, col = wc*64 + c*16 + n16
  int4 li4[4];
#pragma unroll
  for (int r = 0; r < 4; ++r)
    li4[r] = *(const int4*)(labels + iBase + wr * 64 + r * 16 + quad * 4);
  int lj[4];
#pragma unroll
  for (int c = 0; c < 4; ++c) lj[c] = labels[jBase + wc * 64 + c * 16 + n16];

  float minp[16], maxn[16], cminp[4], cmaxn[4];
#pragma unroll
  for (int k = 0; k < 16; ++k) {
    minp[k] = __builtin_inff();
    maxn[k] = -__builtin_inff();
  }
#pragma unroll
  for (int c = 0; c < 4; ++c) {
    cminp[c] = __builtin_inff();
    cmaxn[c] = -__builtin_inff();
  }

#pragma unroll
  for (int r = 0; r < 4; ++r) {
    const int* lav = (const int*)&li4[r];
#pragma unroll
    for (int c = 0; c < 4; ++c) {
#pragma unroll
      for (int v = 0; v < 4; ++v) {
        float s = acc[r][c][v];
        bool same = (lav[v] == lj[c]);
        float pv = same ? s : __builtin_inff();
        float nv = same ? -__builtin_inff() : s;
        if (diag) {
          int row_ = wr * 64 + r * 16 + quad * 4 + v;
          int col_ = wc * 64 + c * 16 + n16;
          if (row_ == col_) pv = __builtin_inff(); // exclude self from positives
        }
        int k = r * 4 + v;
        minp[k] = fminf(minp[k], pv);
        maxn[k] = fmaxf(maxn[k], nv);
        cminp[c] = fminf(cminp[c], same ? s : __builtin_inff());
        cmaxn[c] = fmaxf(cmaxn[c], same ? -__builtin_inff() : s);
      }
    }
  }

  // row-side: butterfly across the 16 n16-lanes sharing the same rows
#pragma unroll
  for (int m = 1; m <= 8; m <<= 1) {
#pragma unroll
    for (int k = 0; k < 16; ++k) {
      minp[k] = fminf(minp[k], __shfl_xor(minp[k], m, 64));
      maxn[k] = fmaxf(maxn[k], __shfl_xor(maxn[k], m, 64));
    }
  }
  if (n16 == 0) {
#pragma unroll
    for (int k = 0; k < 16; ++k) {
      int row = iBase + wr * 64 + (k >> 2) * 16 + quad * 4 + (k & 3);
      atomicMin(&minpos_enc[row], enc_f32(minp[k]));
      atomicMax(&maxneg_enc[row], enc_f32(maxn[k]));
    }
  }

  // col-side (transpose mining): butterfly across the 4 quads
  if (!diag) {
#pragma unroll
    for (int m = 16; m <= 32; m <<= 1) {
#pragma unroll
      for (int c = 0; c < 4; ++c) {
        cminp[c] = fminf(cminp[c], __shfl_xor(cminp[c], m, 64));
        cmaxn[c] = fmaxf(cmaxn[c], __shfl_xor(cmaxn[c], m, 64));
      }
    }
    if (quad == 0) {
#pragma unroll
      for (int c = 0; c < 4; ++c) {
        int row = jBase + wc * 64 + c * 16 + n16;
        atomicMin(&minpos_enc[row], enc_f32(cminp[c]));
        atomicMax(&maxneg_enc[row], enc_f32(cmaxn[c]));
      }
    }
  }
}

// ---- kernel 3: loss = mean(relu(maxneg_s - minpos_s + margin)) ----
__global__ __launch_bounds__(256) void finalize_loss(
    const int* __restrict__ minpos_enc, const int* __restrict__ maxneg_enc,
    float* __restrict__ out) {
  const int tid = threadIdx.x;
  const int4* mp4 = (const int4*)minpos_enc;
  const int4* mn4 = (const int4*)maxneg_enc;
  float sum = 0.f;
#pragma unroll
  for (int i = 0; i < 8; ++i) {
    int idx = i * 256 + tid; // 2048 int4 = 8192 entries
    int4 a = mp4[idx];
    int4 b = mn4[idx];
    const int* ap = (const int*)&a;
    const int* bp = (const int*)&b;
#pragma unroll
    for (int v = 0; v < 4; ++v) {
      float loss = dec_f32(bp[v]) - dec_f32(ap[v]) + MARGIN;
      sum += loss > 0.f ? loss : 0.f; // relu(-inf) = 0 matches jnp
    }
  }
#pragma unroll
  for (int m = 1; m < 64; m <<= 1) sum += __shfl_xor(sum, m, 64);
  __shared__ float ws4[4];
  const int lane = tid & 63, wave = tid >> 6;
  if (lane == 0) ws4[wave] = sum;
  __syncthreads();
  if (tid == 0) out[0] = (ws4[0] + ws4[1] + ws4[2] + ws4[3]) * (1.0f / N);
}

extern "C" void kernel_launch(void* const* d_in, const int* in_sizes, int n_in,
                              void* d_out, int out_size, void* d_ws, size_t ws_size,
                              hipStream_t stream) {
  const float* emb = (const float*)d_in[0];
  const int* labels = (const int*)d_in[1];
  float* out = (float*)d_out;

  unsigned short* e = (unsigned short*)d_ws; // N*D bf16 = 8 MB
  int* minpos_enc = (int*)((char*)d_ws + (size_t)N * D * sizeof(unsigned short));
  int* maxneg_enc = minpos_enc + N;

  normalize_rows<<<N / 4, 256, 0, stream>>>(emb, e, minpos_enc, maxneg_enc);
  bh_gemm_sym<<<NPAIR, 256, 0, stream>>>(e, labels, minpos_enc, maxneg_enc);
  finalize_loss<<<1, 256, 0, stream>>>(minpos_enc, maxneg_enc, out);
}

// Round 4
// 140.564 us; speedup vs baseline: 1.3190x; 1.3190x over previous
//
#include <hip/hip_runtime.h>
#include <stdint.h>

#define MARGIN 0.3f

constexpr int N = 8192;
constexpr int D = 512;
constexpr int BM = 128, BN = 128, BK = 32;
constexpr int NCHUNK = D / BK;                // 16
constexpr int NT = N / BM;                    // 64 tiles per side
constexpr int NPAIR = NT * (NT + 1) / 2;      // 2080 unordered tile pairs
constexpr int WEDGE = NPAIR / 8;              // 260 pairs per XCD wedge

typedef short bf16x8 __attribute__((ext_vector_type(8)));
typedef float f32x4 __attribute__((ext_vector_type(4)));

__device__ __forceinline__ int enc_f32(float f) {
  int b = __float_as_int(f);
  return b >= 0 ? b : (b ^ 0x7fffffff);
}
__device__ __forceinline__ float dec_f32(int k) {
  return __int_as_float(k >= 0 ? k : (k ^ 0x7fffffff));
}

__device__ __forceinline__ unsigned short f2bf(float f) {
  unsigned u = __float_as_uint(f);
  u += 0x7fffu + ((u >> 16) & 1u); // RNE
  return (unsigned short)(u >> 16);
}

__device__ __forceinline__ void load_lds16(const unsigned short* g, short* l) {
  __builtin_amdgcn_global_load_lds((const __attribute__((address_space(1))) void*)g,
                                   (__attribute__((address_space(3))) void*)l,
                                   16, 0, 0);
}

// Decode pair index q (super-tile-major enumeration of the lower triangle)
// into (ti, tj), ti >= tj. Super-tile = 8x8 tiles; base(SI) = 32*SI^2 + 4*SI.
__device__ __forceinline__ void pair_from_q(int q, int& ti, int& tj) {
  int SI = 0;
  while (32 * (SI + 1) * (SI + 1) + 4 * (SI + 1) <= q) ++SI;
  int r = q - (32 * SI * SI + 4 * SI);
  int i, j, SJ;
  if (r < 64 * SI) {
    SJ = r >> 6;
    int w = r & 63;
    i = w >> 3;
    j = w & 7;
  } else {
    int d = r - 64 * SI;
    SJ = SI;
    i = 0;
    while ((i + 1) * (i + 2) / 2 <= d) ++i;
    j = d - i * (i + 1) / 2;
  }
  ti = SI * 8 + i;
  tj = SJ * 8 + j;
}

// ---- kernel 1: L2-normalize rows -> bf16; init min/max arrays ----
__global__ __launch_bounds__(256) void normalize_rows(
    const float* __restrict__ emb, unsigned short* __restrict__ e,
    int* __restrict__ minpos_enc, int* __restrict__ maxneg_enc) {
  const int wave = threadIdx.x >> 6, lane = threadIdx.x & 63;
  const int row = blockIdx.x * 4 + wave;
  const float4* src = (const float4*)(emb + (size_t)row * D);
  float4 x0 = src[lane];
  float4 x1 = src[lane + 64];
  float ss = x0.x * x0.x + x0.y * x0.y + x0.z * x0.z + x0.w * x0.w +
             x1.x * x1.x + x1.y * x1.y + x1.z * x1.z + x1.w * x1.w;
#pragma unroll
  for (int m = 1; m < 64; m <<= 1) ss += __shfl_xor(ss, m, 64);
  float r = rsqrtf(ss);
  ushort4 o0 = {f2bf(x0.x * r), f2bf(x0.y * r), f2bf(x0.z * r), f2bf(x0.w * r)};
  ushort4 o1 = {f2bf(x1.x * r), f2bf(x1.y * r), f2bf(x1.z * r), f2bf(x1.w * r)};
  ushort4* dst = (ushort4*)(e + (size_t)row * D);
  dst[lane] = o0;
  dst[lane + 64] = o1;
  if (lane == 0) {
    minpos_enc[row] = 0x7f800000;      // enc(+inf)
    maxneg_enc[row] = (int)0x807fffff; // enc(-inf)
  }
}

// ---- kernel 2: symmetric fused Gram-tile GEMM + batch-hard mining ----
// 2080 blocks; block b -> pair q = 260*(b%8) + b/8 (XCD-wedge, L2-local).
// K-loop: double-buffered LDS, raw s_barrier + manual vmcnt(4) so the
// prefetch for chunk k+1 stays in flight across chunk k's barrier.
__global__ __launch_bounds__(256) void bh_gemm_sym(
    const unsigned short* __restrict__ e, const int* __restrict__ labels,
    int* __restrict__ minpos_enc, int* __restrict__ maxneg_enc) {
  __shared__ short As[2][BM * BK]; // 2 x 8 KB, [row][slot], slot=seg^((row>>1)&3)
  __shared__ short Bs[2][BN * BK]; // 2 x 8 KB

  const int b = blockIdx.x;
  const int q = WEDGE * (b & 7) + (b >> 3);
  int ti, tj;
  pair_from_q(q, ti, tj);
  const int iBase = ti * BM, jBase = tj * BN;
  const bool diag = (ti == tj);

  const int tid = threadIdx.x;
  const int lane = tid & 63;
  const int wave = tid >> 6;
  const int wr = wave >> 1, wc = wave & 1;
  const int quad = lane >> 4, n16 = lane & 15;

  // per-thread staging source rows/segments (2 slots of 16B per array)
  const int q0 = tid, q1 = 256 + tid;
  const int row0 = q0 >> 2, seg0 = (q0 & 3) ^ ((row0 >> 1) & 3);
  const int row1 = q1 >> 2, seg1 = (q1 & 3) ^ ((row1 >> 1) & 3);
  const unsigned short* a0 = e + (size_t)(iBase + row0) * D + seg0 * 8;
  const unsigned short* a1 = e + (size_t)(iBase + row1) * D + seg1 * 8;
  const unsigned short* b0 = e + (size_t)(jBase + row0) * D + seg0 * 8;
  const unsigned short* b1 = e + (size_t)(jBase + row1) * D + seg1 * 8;

  auto stage = [&](int buf, int kc) {
    const int k0 = kc * BK;
    load_lds16(a0 + k0, &As[buf][q0 * 8]);
    load_lds16(b0 + k0, &Bs[buf][q0 * 8]);
    load_lds16(a1 + k0, &As[buf][q1 * 8]);
    load_lds16(b1 + k0, &Bs[buf][q1 * 8]);
  };

  f32x4 acc[4][4];
#pragma unroll
  for (int r = 0; r < 4; ++r)
#pragma unroll
    for (int c = 0; c < 4; ++c) acc[r][c] = (f32x4)0.0f;

  // LDS read offsets (element index) for this lane's fragments
  int offA[4], offB[4];
#pragma unroll
  for (int r = 0; r < 4; ++r) {
    int rowa = wr * 64 + r * 16 + n16;
    offA[r] = rowa * BK + (quad ^ ((rowa >> 1) & 3)) * 8;
    int rowb = wc * 64 + r * 16 + n16;
    offB[r] = rowb * BK + (quad ^ ((rowb >> 1) & 3)) * 8;
  }

  auto compute = [&](int buf) {
    bf16x8 af[4], bfr[4];
    const short* ab = As[buf];
    const short* bb = Bs[buf];
#pragma unroll
    for (int r = 0; r < 4; ++r) af[r] = *(const bf16x8*)(ab + offA[r]);
#pragma unroll
    for (int c = 0; c < 4; ++c) bfr[c] = *(const bf16x8*)(bb + offB[c]);
#pragma unroll
    for (int r = 0; r < 4; ++r)
#pragma unroll
      for (int c = 0; c < 4; ++c)
        acc[r][c] = __builtin_amdgcn_mfma_f32_16x16x32_bf16(af[r], bfr[c], acc[r][c], 0, 0, 0);
  };

  stage(0, 0); // prologue: chunk 0 into buffer 0

  for (int k = 0; k < NCHUNK - 1; ++k) {
    stage((k + 1) & 1, k + 1);                      // prefetch next chunk
    asm volatile("s_waitcnt vmcnt(4)" ::: "memory"); // wait older chunk only
    asm volatile("s_barrier" ::: "memory");          // all waves: buf[k] ready
    compute(k & 1);
    asm volatile("s_barrier" ::: "memory");          // all waves done reading
  }
  asm volatile("s_waitcnt vmcnt(0)" ::: "memory");
  asm volatile("s_barrier" ::: "memory");
  compute((NCHUNK - 1) & 1);

  // ---- epilogue: batch-hard mining ----
  // C/D layout: row = wr*64 + r*16 + quad*4 + v, col = wc*64 + c*16 + n16
  int lj[4];
#pragma unroll
  for (int c = 0; c < 4; ++c) lj[c] = labels[jBase + wc * 64 + c * 16 + n16];

  float cminp[4], cmaxn[4]; // col-side (transpose) mining, live across r
#pragma unroll
  for (int c = 0; c < 4; ++c) {
    cminp[c] = __builtin_inff();
    cmaxn[c] = -__builtin_inff();
  }

#pragma unroll
  for (int r = 0; r < 4; ++r) {
    const int rbase = wr * 64 + r * 16 + quad * 4; // row offset within tile
    int4 li = *(const int4*)(labels + iBase + rbase);
    const int* lav = (const int*)&li;
    float minp[4], maxn[4];
#pragma unroll
    for (int v = 0; v < 4; ++v) {
      minp[v] = __builtin_inff();
      maxn[v] = -__builtin_inff();
    }
#pragma unroll
    for (int c = 0; c < 4; ++c) {
      const int col_ = wc * 64 + c * 16 + n16;
#pragma unroll
      for (int v = 0; v < 4; ++v) {
        float s = acc[r][c][v];
        bool same = (lav[v] == lj[c]);
        float pv = same ? s : __builtin_inff();
        float nv = same ? -__builtin_inff() : s;
        if (diag && (rbase + v) == col_) pv = __builtin_inff(); // exclude self
        minp[v] = fminf(minp[v], pv);
        maxn[v] = fmaxf(maxn[v], nv);
        cminp[c] = fminf(cminp[c], same ? s : __builtin_inff());
        cmaxn[c] = fmaxf(cmaxn[c], same ? -__builtin_inff() : s);
      }
    }
    // butterfly across the 16 n16-lanes sharing these 4 rows
#pragma unroll
    for (int m = 1; m <= 8; m <<= 1) {
#pragma unroll
      for (int v = 0; v < 4; ++v) {
        minp[v] = fminf(minp[v], __shfl_xor(minp[v], m, 64));
        maxn[v] = fmaxf(maxn[v], __shfl_xor(maxn[v], m, 64));
      }
    }
    if (n16 == 0) {
#pragma unroll
      for (int v = 0; v < 4; ++v) {
        int row = iBase + rbase + v;
        atomicMin(&minpos_enc[row], enc_f32(minp[v]));
        atomicMax(&maxneg_enc[row], enc_f32(maxn[v]));
      }
    }
  }

  // col-side (transpose mining): butterfly across the 4 quads
  if (!diag) {
#pragma unroll
    for (int m = 16; m <= 32; m <<= 1) {
#pragma unroll
      for (int c = 0; c < 4; ++c) {
        cminp[c] = fminf(cminp[c], __shfl_xor(cminp[c], m, 64));
        cmaxn[c] = fmaxf(cmaxn[c], __shfl_xor(cmaxn[c], m, 64));
      }
    }
    if (quad == 0) {
#pragma unroll
      for (int c = 0; c < 4; ++c) {
        int row = jBase + wc * 64 + c * 16 + n16;
        atomicMin(&minpos_enc[row], enc_f32(cminp[c]));
        atomicMax(&maxneg_enc[row], enc_f32(cmaxn[c]));
      }
    }
  }
}

// ---- kernel 3: loss = mean(relu(maxneg_s - minpos_s + margin)) ----
__global__ __launch_bounds__(256) void finalize_loss(
    const int* __restrict__ minpos_enc, const int* __restrict__ maxneg_enc,
    float* __restrict__ out) {
  const int tid = threadIdx.x;
  const int4* mp4 = (const int4*)minpos_enc;
  const int4* mn4 = (const int4*)maxneg_enc;
  float sum = 0.f;
#pragma unroll
  for (int i = 0; i < 8; ++i) {
    int idx = i * 256 + tid;
    int4 a = mp4[idx];
    int4 b = mn4[idx];
    const int* ap = (const int*)&a;
    const int* bp = (const int*)&b;
#pragma unroll
    for (int v = 0; v < 4; ++v) {
      float loss = dec_f32(bp[v]) - dec_f32(ap[v]) + MARGIN;
      sum += loss > 0.f ? loss : 0.f; // relu(-inf) = 0 matches jnp
    }
  }
#pragma unroll
  for (int m = 1; m < 64; m <<= 1) sum += __shfl_xor(sum, m, 64);
  __shared__ float ws4[4];
  const int lane = tid & 63, wave = tid >> 6;
  if (lane == 0) ws4[wave] = sum;
  __syncthreads();
  if (tid == 0) out[0] = (ws4[0] + ws4[1] + ws4[2] + ws4[3]) * (1.0f / N);
}

extern "C" void kernel_launch(void* const* d_in, const int* in_sizes, int n_in,
                              void* d_out, int out_size, void* d_ws, size_t ws_size,
                              hipStream_t stream) {
  const float* emb = (const float*)d_in[0];
  const int* labels = (const int*)d_in[1];
  float* out = (float*)d_out;

  unsigned short* e = (unsigned short*)d_ws; // N*D bf16 = 8 MB
  int* minpos_enc = (int*)((char*)d_ws + (size_t)N * D * sizeof(unsigned short));
  int* maxneg_enc = minpos_enc + N;

  normalize_rows<<<N / 4, 256, 0, stream>>>(emb, e, minpos_enc, maxneg_enc);
  bh_gemm_sym<<<NPAIR, 256, 0, stream>>>(e, labels, minpos_enc, maxneg_enc);
  finalize_loss<<<1, 256, 0, stream>>>(minpos_enc, maxneg_enc, out);
}

// Round 5
// 130.629 us; speedup vs baseline: 1.4193x; 1.0761x over previous
//
#include <hip/hip_runtime.h>
#include <stdint.h>

#define MARGIN 0.3f

constexpr int N = 8192;
constexpr int D = 512;
constexpr int BM = 128, BN = 128, BK = 32;
constexpr int NCHUNK = D / BK;                // 16
constexpr int NT = N / BM;                    // 64 tiles per side
constexpr int NPAIR = NT * (NT + 1) / 2;      // 2080 unordered tile pairs
constexpr int WEDGE = NPAIR / 8;              // 260 pairs per XCD wedge

typedef short bf16x8 __attribute__((ext_vector_type(8)));
typedef float f32x4 __attribute__((ext_vector_type(4)));

__device__ __forceinline__ int enc_f32(float f) {
  int b = __float_as_int(f);
  return b >= 0 ? b : (b ^ 0x7fffffff);
}
__device__ __forceinline__ float dec_f32(int k) {
  return __int_as_float(k >= 0 ? k : (k ^ 0x7fffffff));
}

__device__ __forceinline__ unsigned short f2bf(float f) {
  unsigned u = __float_as_uint(f);
  u += 0x7fffu + ((u >> 16) & 1u); // RNE
  return (unsigned short)(u >> 16);
}

__device__ __forceinline__ void load_lds16(const unsigned short* g, short* l) {
  __builtin_amdgcn_global_load_lds((const __attribute__((address_space(1))) void*)g,
                                   (__attribute__((address_space(3))) void*)l,
                                   16, 0, 0);
}

// Decode pair index q (super-tile-major enumeration of the lower triangle)
// into (ti, tj), ti >= tj. Super-tile = 8x8 tiles; base(SI) = 32*SI^2 + 4*SI.
__device__ __forceinline__ void pair_from_q(int q, int& ti, int& tj) {
  int SI = 0;
  while (32 * (SI + 1) * (SI + 1) + 4 * (SI + 1) <= q) ++SI;
  int r = q - (32 * SI * SI + 4 * SI);
  int i, j, SJ;
  if (r < 64 * SI) {
    SJ = r >> 6;
    int w = r & 63;
    i = w >> 3;
    j = w & 7;
  } else {
    int d = r - 64 * SI;
    SJ = SI;
    i = 0;
    while ((i + 1) * (i + 2) / 2 <= d) ++i;
    j = d - i * (i + 1) / 2;
  }
  ti = SI * 8 + i;
  tj = SJ * 8 + j;
}

// ---- kernel 1: L2-normalize rows -> bf16; init min/max arrays ----
__global__ __launch_bounds__(256) void normalize_rows(
    const float* __restrict__ emb, unsigned short* __restrict__ e,
    int* __restrict__ minpos_enc, int* __restrict__ maxneg_enc) {
  const int wave = threadIdx.x >> 6, lane = threadIdx.x & 63;
  const int row = blockIdx.x * 4 + wave;
  const float4* src = (const float4*)(emb + (size_t)row * D);
  float4 x0 = src[lane];
  float4 x1 = src[lane + 64];
  float ss = x0.x * x0.x + x0.y * x0.y + x0.z * x0.z + x0.w * x0.w +
             x1.x * x1.x + x1.y * x1.y + x1.z * x1.z + x1.w * x1.w;
#pragma unroll
  for (int m = 1; m < 64; m <<= 1) ss += __shfl_xor(ss, m, 64);
  float r = rsqrtf(ss);
  ushort4 o0 = {f2bf(x0.x * r), f2bf(x0.y * r), f2bf(x0.z * r), f2bf(x0.w * r)};
  ushort4 o1 = {f2bf(x1.x * r), f2bf(x1.y * r), f2bf(x1.z * r), f2bf(x1.w * r)};
  ushort4* dst = (ushort4*)(e + (size_t)row * D);
  dst[lane] = o0;
  dst[lane + 64] = o1;
  if (lane == 0) {
    minpos_enc[row] = 0x7f800000;      // enc(+inf)
    maxneg_enc[row] = (int)0x807fffff; // enc(-inf)
  }
}

// ---- kernel 2: symmetric fused Gram-tile GEMM + batch-hard mining ----
// 2080 blocks; block b -> pair q = 260*(b%8) + b/8 (XCD-wedge, L2-local).
// K-loop: 3-buffer LDS, depth-2 prefetch, raw s_barrier + vmcnt(8) so two
// chunks' staging loads stay in flight across each barrier.
__global__ __launch_bounds__(256, 3) void bh_gemm_sym(
    const unsigned short* __restrict__ e, const int* __restrict__ labels,
    int* __restrict__ minpos_enc, int* __restrict__ maxneg_enc) {
  __shared__ short As[3][BM * BK]; // 3 x 8 KB, [row][slot], slot=seg^((row>>1)&3)
  __shared__ short Bs[3][BN * BK]; // 3 x 8 KB  (48 KB total -> 3 blocks/CU)

  const int b = blockIdx.x;
  const int q = WEDGE * (b & 7) + (b >> 3);
  int ti, tj;
  pair_from_q(q, ti, tj);
  const int iBase = ti * BM, jBase = tj * BN;
  const bool diag = (ti == tj);

  const int tid = threadIdx.x;
  const int lane = tid & 63;
  const int wave = tid >> 6;
  const int wr = wave >> 1, wc = wave & 1;
  const int quad = lane >> 4, n16 = lane & 15;

  // staging: thread covers 16B slots q0=tid (rows 0..63) and q1=256+tid
  // (rows 64..127); global seg = pos ^ ((row>>1)&3) (bank de-swizzle).
  const int q0 = tid, q1 = 256 + tid;
  const int row0 = q0 >> 2, seg0 = (q0 & 3) ^ ((row0 >> 1) & 3);
  const int row1 = q1 >> 2, seg1 = (q1 & 3) ^ ((row1 >> 1) & 3);
  // 32-bit element indices (saddr+voffset addressing, 1 VGPR each)
  const unsigned ia0 = (unsigned)(iBase + row0) * D + seg0 * 8;
  const unsigned ia1 = (unsigned)(iBase + row1) * D + seg1 * 8;
  const unsigned ib0 = (unsigned)(jBase + row0) * D + seg0 * 8;
  const unsigned ib1 = (unsigned)(jBase + row1) * D + seg1 * 8;

  auto stage = [&](int buf, int kc) {
    const unsigned k0 = kc * BK;
    load_lds16(e + (ia0 + k0), &As[buf][q0 * 8]);
    load_lds16(e + (ib0 + k0), &Bs[buf][q0 * 8]);
    load_lds16(e + (ia1 + k0), &As[buf][q1 * 8]);
    load_lds16(e + (ib1 + k0), &Bs[buf][q1 * 8]);
  };

  f32x4 acc[4][4];
#pragma unroll
  for (int r = 0; r < 4; ++r)
#pragma unroll
    for (int c = 0; c < 4; ++c) acc[r][c] = (f32x4)0.0f;

  // LDS read bases: swizzle slot = quad ^ ((n16>>1)&3) (frag-independent);
  // frag r/c is at base + {r,c}*16*BK.
  const int slot = quad ^ ((n16 >> 1) & 3);
  const int baseA = (wr * 64 + n16) * BK + slot * 8;
  const int baseB = (wc * 64 + n16) * BK + slot * 8;

  auto compute = [&](int buf) {
    bf16x8 af[4], bfr[4];
    const short* ab = As[buf];
    const short* bb = Bs[buf];
#pragma unroll
    for (int r = 0; r < 4; ++r) af[r] = *(const bf16x8*)(ab + baseA + r * 16 * BK);
#pragma unroll
    for (int c = 0; c < 4; ++c) bfr[c] = *(const bf16x8*)(bb + baseB + c * 16 * BK);
#pragma unroll
    for (int r = 0; r < 4; ++r)
#pragma unroll
      for (int c = 0; c < 4; ++c)
        acc[r][c] = __builtin_amdgcn_mfma_f32_16x16x32_bf16(af[r], bfr[c], acc[r][c], 0, 0, 0);
  };

  stage(0, 0); // prologue: chunks 0,1 in flight
  stage(1, 1);

#pragma unroll
  for (int k = 0; k < NCHUNK; ++k) {
    if (k + 2 < NCHUNK) {
      stage((k + 2) % 3, k + 2);                     // prefetch depth 2
      asm volatile("s_waitcnt vmcnt(8)" ::: "memory"); // oldest chunk done
    } else if (k + 1 < NCHUNK) {
      asm volatile("s_waitcnt vmcnt(4)" ::: "memory");
    } else {
      asm volatile("s_waitcnt vmcnt(0)" ::: "memory");
    }
    asm volatile("s_barrier" ::: "memory"); // buf[k] visible to all waves
    compute(k % 3);
    asm volatile("s_barrier" ::: "memory"); // readers done before overwrite
  }

  // ---- epilogue: batch-hard mining ----
  // C/D layout: row = wr*64 + r*16 + quad*4 + v, col = wc*64 + c*16 + n16
  int lj[4];
#pragma unroll
  for (int c = 0; c < 4; ++c) lj[c] = labels[jBase + wc * 64 + c * 16 + n16];

  float cminp[4], cmaxn[4]; // col-side (transpose) mining, live across r
#pragma unroll
  for (int c = 0; c < 4; ++c) {
    cminp[c] = __builtin_inff();
    cmaxn[c] = -__builtin_inff();
  }

#pragma unroll
  for (int r = 0; r < 4; ++r) {
    const int rbase = wr * 64 + r * 16 + quad * 4; // row offset within tile
    int4 li = *(const int4*)(labels + iBase + rbase);
    const int* lav = (const int*)&li;
    float minp[4], maxn[4];
#pragma unroll
    for (int v = 0; v < 4; ++v) {
      minp[v] = __builtin_inff();
      maxn[v] = -__builtin_inff();
    }
#pragma unroll
    for (int c = 0; c < 4; ++c) {
      const int col_ = wc * 64 + c * 16 + n16;
#pragma unroll
      for (int v = 0; v < 4; ++v) {
        float s = acc[r][c][v];
        bool same = (lav[v] == lj[c]);
        float pv = same ? s : __builtin_inff();
        float nv = same ? -__builtin_inff() : s;
        if (diag && (rbase + v) == col_) pv = __builtin_inff(); // exclude self
        minp[v] = fminf(minp[v], pv);
        maxn[v] = fmaxf(maxn[v], nv);
        cminp[c] = fminf(cminp[c], same ? s : __builtin_inff());
        cmaxn[c] = fmaxf(cmaxn[c], same ? -__builtin_inff() : s);
      }
    }
    // butterfly across the 16 n16-lanes sharing these 4 rows
#pragma unroll
    for (int m = 1; m <= 8; m <<= 1) {
#pragma unroll
      for (int v = 0; v < 4; ++v) {
        minp[v] = fminf(minp[v], __shfl_xor(minp[v], m, 64));
        maxn[v] = fmaxf(maxn[v], __shfl_xor(maxn[v], m, 64));
      }
    }
    if (n16 == 0) {
#pragma unroll
      for (int v = 0; v < 4; ++v) {
        int row = iBase + rbase + v;
        atomicMin(&minpos_enc[row], enc_f32(minp[v]));
        atomicMax(&maxneg_enc[row], enc_f32(maxn[v]));
      }
    }
  }

  // col-side (transpose mining): butterfly across the 4 quads
  if (!diag) {
#pragma unroll
    for (int m = 16; m <= 32; m <<= 1) {
#pragma unroll
      for (int c = 0; c < 4; ++c) {
        cminp[c] = fminf(cminp[c], __shfl_xor(cminp[c], m, 64));
        cmaxn[c] = fmaxf(cmaxn[c], __shfl_xor(cmaxn[c], m, 64));
      }
    }
    if (quad == 0) {
#pragma unroll
      for (int c = 0; c < 4; ++c) {
        int row = jBase + wc * 64 + c * 16 + n16;
        atomicMin(&minpos_enc[row], enc_f32(cminp[c]));
        atomicMax(&maxneg_enc[row], enc_f32(cmaxn[c]));
      }
    }
  }
}

// ---- kernel 3: loss = mean(relu(maxneg_s - minpos_s + margin)) ----
__global__ __launch_bounds__(256) void finalize_loss(
    const int* __restrict__ minpos_enc, const int* __restrict__ maxneg_enc,
    float* __restrict__ out) {
  const int tid = threadIdx.x;
  const int4* mp4 = (const int4*)minpos_enc;
  const int4* mn4 = (const int4*)maxneg_enc;
  float sum = 0.f;
#pragma unroll
  for (int i = 0; i < 8; ++i) {
    int idx = i * 256 + tid;
    int4 a = mp4[idx];
    int4 b = mn4[idx];
    const int* ap = (const int*)&a;
    const int* bp = (const int*)&b;
#pragma unroll
    for (int v = 0; v < 4; ++v) {
      float loss = dec_f32(bp[v]) - dec_f32(ap[v]) + MARGIN;
      sum += loss > 0.f ? loss : 0.f; // relu(-inf) = 0 matches jnp
    }
  }
#pragma unroll
  for (int m = 1; m < 64; m <<= 1) sum += __shfl_xor(sum, m, 64);
  __shared__ float ws4[4];
  const int lane = tid & 63, wave = tid >> 6;
  if (lane == 0) ws4[wave] = sum;
  __syncthreads();
  if (tid == 0) out[0] = (ws4[0] + ws4[1] + ws4[2] + ws4[3]) * (1.0f / N);
}

extern "C" void kernel_launch(void* const* d_in, const int* in_sizes, int n_in,
                              void* d_out, int out_size, void* d_ws, size_t ws_size,
                              hipStream_t stream) {
  const float* emb = (const float*)d_in[0];
  const int* labels = (const int*)d_in[1];
  float* out = (float*)d_out;

  unsigned short* e = (unsigned short*)d_ws; // N*D bf16 = 8 MB
  int* minpos_enc = (int*)((char*)d_ws + (size_t)N * D * sizeof(unsigned short));
  int* maxneg_enc = minpos_enc + N;

  normalize_rows<<<N / 4, 256, 0, stream>>>(emb, e, minpos_enc, maxneg_enc);
  bh_gemm_sym<<<NPAIR, 256, 0, stream>>>(e, labels, minpos_enc, maxneg_enc);
  finalize_loss<<<1, 256, 0, stream>>>(minpos_enc, maxneg_enc, out);
}

// Round 6
// 129.147 us; speedup vs baseline: 1.4356x; 1.0115x over previous
//
#include <hip/hip_runtime.h>
#include <hip/hip_fp8.h>
#include <stdint.h>

#define MARGIN 0.3f

constexpr int N = 8192;
constexpr int D = 512;
constexpr int BM = 128, BN = 128, BK = 64;    // fp8: 64-wide K chunks
constexpr int NCHUNK = D / BK;                // 8
constexpr int NT = N / BM;                    // 64 tiles per side
constexpr int NPAIR = NT * (NT + 1) / 2;      // 2080 unordered tile pairs
constexpr int WEDGE = NPAIR / 8;              // 260 pairs per XCD wedge
constexpr float ESCALE = 16.0f;               // fp8 pre-scale
constexpr float INV_SC2 = 1.0f / (ESCALE * ESCALE);

typedef float f32x4 __attribute__((ext_vector_type(4)));

__device__ __forceinline__ int enc_f32(float f) {
  int b = __float_as_int(f);
  return b >= 0 ? b : (b ^ 0x7fffffff);
}
__device__ __forceinline__ float dec_f32(int k) {
  return __int_as_float(k >= 0 ? k : (k ^ 0x7fffffff));
}

__device__ __forceinline__ unsigned char f2fp8(float f) {
  return __hip_fp8_e4m3(f).__x; // OCP e4m3fn, RNE+sat
}

__device__ __forceinline__ void load_lds16(const unsigned char* g, unsigned char* l) {
  __builtin_amdgcn_global_load_lds((const __attribute__((address_space(1))) void*)g,
                                   (__attribute__((address_space(3))) void*)l,
                                   16, 0, 0);
}

// Decode pair index q (super-tile-major enumeration of the lower triangle)
// into (ti, tj), ti >= tj. Super-tile = 8x8 tiles; base(SI) = 32*SI^2 + 4*SI.
__device__ __forceinline__ void pair_from_q(int q, int& ti, int& tj) {
  int SI = 0;
  while (32 * (SI + 1) * (SI + 1) + 4 * (SI + 1) <= q) ++SI;
  int r = q - (32 * SI * SI + 4 * SI);
  int i, j, SJ;
  if (r < 64 * SI) {
    SJ = r >> 6;
    int w = r & 63;
    i = w >> 3;
    j = w & 7;
  } else {
    int d = r - 64 * SI;
    SJ = SI;
    i = 0;
    while ((i + 1) * (i + 2) / 2 <= d) ++i;
    j = d - i * (i + 1) / 2;
  }
  ti = SI * 8 + i;
  tj = SJ * 8 + j;
}

// ---- kernel 1: L2-normalize rows -> fp8 e4m3 (x16); init min/max arrays ----
__global__ __launch_bounds__(256) void normalize_rows(
    const float* __restrict__ emb, unsigned char* __restrict__ e8,
    int* __restrict__ minpos_enc, int* __restrict__ maxneg_enc) {
  const int wave = threadIdx.x >> 6, lane = threadIdx.x & 63;
  const int row = blockIdx.x * 4 + wave;
  const float4* src = (const float4*)(emb + (size_t)row * D);
  float4 x0 = src[lane];
  float4 x1 = src[lane + 64];
  float ss = x0.x * x0.x + x0.y * x0.y + x0.z * x0.z + x0.w * x0.w +
             x1.x * x1.x + x1.y * x1.y + x1.z * x1.z + x1.w * x1.w;
#pragma unroll
  for (int m = 1; m < 64; m <<= 1) ss += __shfl_xor(ss, m, 64);
  const float r = rsqrtf(ss) * ESCALE;
  union { unsigned char b[8]; uint2 u; } o;
  o.b[0] = f2fp8(x0.x * r); o.b[1] = f2fp8(x0.y * r);
  o.b[2] = f2fp8(x0.z * r); o.b[3] = f2fp8(x0.w * r);
  o.b[4] = f2fp8(x1.x * r); o.b[5] = f2fp8(x1.y * r);
  o.b[6] = f2fp8(x1.z * r); o.b[7] = f2fp8(x1.w * r);
  ((uint2*)(e8 + (size_t)row * D))[lane] = o.u; // lane covers els 8*lane..8*lane+7
  if (lane == 0) {
    minpos_enc[row] = 0x7f800000;      // enc(+inf)
    maxneg_enc[row] = (int)0x807fffff; // enc(-inf)
  }
}

// ---- kernel 2: symmetric fused fp8 Gram-tile GEMM + batch-hard mining ----
// 2080 blocks; block b -> pair q = 260*(b%8) + b/8 (XCD-wedge, L2-local).
// K-loop: 3-buffer LDS, depth-2 prefetch, raw s_barrier + vmcnt(8).
// LDS rows are 64 B of fp8; 16B granules XOR-swizzled by (row&3).
__global__ __launch_bounds__(256, 3) void bh_gemm_sym(
    const unsigned char* __restrict__ e8, const int* __restrict__ labels,
    int* __restrict__ minpos_enc, int* __restrict__ maxneg_enc) {
  __shared__ __align__(16) unsigned char As[3][BM * BK]; // 3 x 8 KB
  __shared__ __align__(16) unsigned char Bs[3][BN * BK]; // 3 x 8 KB (48 KB)

  const int b = blockIdx.x;
  const int q = WEDGE * (b & 7) + (b >> 3);
  int ti, tj;
  pair_from_q(q, ti, tj);
  const int iBase = ti * BM, jBase = tj * BN;
  const bool diag = (ti == tj);

  const int tid = threadIdx.x;
  const int lane = tid & 63;
  const int wave = tid >> 6;
  const int wr = wave >> 1, wc = wave & 1;
  const int quad = lane >> 4, n16 = lane & 15;

  // staging: 512 16B slots per matrix per chunk; thread covers q0=tid, q1=256+tid.
  // slot q -> row = q>>2, pos = q&3; global seg = pos ^ (row&3) (bank de-swizzle).
  const int q0 = tid, q1 = 256 + tid;
  const int row0 = q0 >> 2, seg0 = (q0 & 3) ^ (row0 & 3);
  const int row1 = q1 >> 2, seg1 = (q1 & 3) ^ (row1 & 3);
  const unsigned ia0 = (unsigned)(iBase + row0) * D + seg0 * 16;
  const unsigned ia1 = (unsigned)(iBase + row1) * D + seg1 * 16;
  const unsigned ib0 = (unsigned)(jBase + row0) * D + seg0 * 16;
  const unsigned ib1 = (unsigned)(jBase + row1) * D + seg1 * 16;

  auto stage = [&](int buf, int kc) {
    const unsigned k0 = kc * BK;
    load_lds16(e8 + (ia0 + k0), &As[buf][q0 * 16]);
    load_lds16(e8 + (ib0 + k0), &Bs[buf][q0 * 16]);
    load_lds16(e8 + (ia1 + k0), &As[buf][q1 * 16]);
    load_lds16(e8 + (ib1 + k0), &Bs[buf][q1 * 16]);
  };

  f32x4 acc[4][4];
#pragma unroll
  for (int r = 0; r < 4; ++r)
#pragma unroll
    for (int c = 0; c < 4; ++c) acc[r][c] = (f32x4)0.0f;

  // frag reads: lane wants k-bytes [a*32 + quad*8 .. +7] of its row (a=0,1).
  // global seg g = a*2 + (quad>>1); LDS pos = g ^ (row&3); row&3 == n16&3.
  const int u = n16 & 3;
  const int off0 = (((quad >> 1) ^ u) * 16) + (quad & 1) * 8;          // a=0
  const int off1 = (((2 + (quad >> 1)) ^ u) * 16) + (quad & 1) * 8;    // a=1
  const int rowA = (wr * 64 + n16) * BK;
  const int rowB = (wc * 64 + n16) * BK;

  auto compute = [&](int buf) {
    const unsigned char* ab = As[buf];
    const unsigned char* bb = Bs[buf];
    long a0[4], a1[4], b0[4], b1[4];
#pragma unroll
    for (int r = 0; r < 4; ++r) {
      a0[r] = *(const long*)(ab + rowA + r * 16 * BK + off0);
      a1[r] = *(const long*)(ab + rowA + r * 16 * BK + off1);
    }
#pragma unroll
    for (int c = 0; c < 4; ++c) {
      b0[c] = *(const long*)(bb + rowB + c * 16 * BK + off0);
      b1[c] = *(const long*)(bb + rowB + c * 16 * BK + off1);
    }
#pragma unroll
    for (int r = 0; r < 4; ++r)
#pragma unroll
      for (int c = 0; c < 4; ++c) {
        acc[r][c] = __builtin_amdgcn_mfma_f32_16x16x32_fp8_fp8(a0[r], b0[c], acc[r][c], 0, 0, 0);
        acc[r][c] = __builtin_amdgcn_mfma_f32_16x16x32_fp8_fp8(a1[r], b1[c], acc[r][c], 0, 0, 0);
      }
  };

  stage(0, 0); // prologue: chunks 0,1 in flight
  stage(1, 1);

#pragma unroll
  for (int k = 0; k < NCHUNK; ++k) {
    if (k + 2 < NCHUNK) {
      stage((k + 2) % 3, k + 2);                       // prefetch depth 2
      asm volatile("s_waitcnt vmcnt(8)" ::: "memory"); // oldest chunk done
    } else if (k + 1 < NCHUNK) {
      asm volatile("s_waitcnt vmcnt(4)" ::: "memory");
    } else {
      asm volatile("s_waitcnt vmcnt(0)" ::: "memory");
    }
    asm volatile("s_barrier" ::: "memory"); // buf[k] visible to all waves
    compute(k % 3);
    asm volatile("s_barrier" ::: "memory"); // readers done before overwrite
  }

  // ---- epilogue: batch-hard mining (similarity = acc / ESCALE^2) ----
  // C/D layout: row = wr*64 + r*16 + quad*4 + v, col = wc*64 + c*16 + n16
  int lj[4];
#pragma unroll
  for (int c = 0; c < 4; ++c) lj[c] = labels[jBase + wc * 64 + c * 16 + n16];

  float cminp[4], cmaxn[4]; // col-side (transpose) mining, live across r
#pragma unroll
  for (int c = 0; c < 4; ++c) {
    cminp[c] = __builtin_inff();
    cmaxn[c] = -__builtin_inff();
  }

#pragma unroll
  for (int r = 0; r < 4; ++r) {
    const int rbase = wr * 64 + r * 16 + quad * 4; // row offset within tile
    int4 li = *(const int4*)(labels + iBase + rbase);
    const int* lav = (const int*)&li;
    float minp[4], maxn[4];
#pragma unroll
    for (int v = 0; v < 4; ++v) {
      minp[v] = __builtin_inff();
      maxn[v] = -__builtin_inff();
    }
#pragma unroll
    for (int c = 0; c < 4; ++c) {
      const int col_ = wc * 64 + c * 16 + n16;
#pragma unroll
      for (int v = 0; v < 4; ++v) {
        float s = acc[r][c][v] * INV_SC2;
        bool same = (lav[v] == lj[c]);
        float pv = same ? s : __builtin_inff();
        float nv = same ? -__builtin_inff() : s;
        if (diag && (rbase + v) == col_) pv = __builtin_inff(); // exclude self
        minp[v] = fminf(minp[v], pv);
        maxn[v] = fmaxf(maxn[v], nv);
        cminp[c] = fminf(cminp[c], same ? s : __builtin_inff());
        cmaxn[c] = fmaxf(cmaxn[c], same ? -__builtin_inff() : s);
      }
    }
    // butterfly across the 16 n16-lanes sharing these 4 rows
#pragma unroll
    for (int m = 1; m <= 8; m <<= 1) {
#pragma unroll
      for (int v = 0; v < 4; ++v) {
        minp[v] = fminf(minp[v], __shfl_xor(minp[v], m, 64));
        maxn[v] = fmaxf(maxn[v], __shfl_xor(maxn[v], m, 64));
      }
    }
    if (n16 == 0) {
#pragma unroll
      for (int v = 0; v < 4; ++v) {
        int row = iBase + rbase + v;
        atomicMin(&minpos_enc[row], enc_f32(minp[v]));
        atomicMax(&maxneg_enc[row], enc_f32(maxn[v]));
      }
    }
  }

  // col-side (transpose mining): butterfly across the 4 quads
  if (!diag) {
#pragma unroll
    for (int m = 16; m <= 32; m <<= 1) {
#pragma unroll
      for (int c = 0; c < 4; ++c) {
        cminp[c] = fminf(cminp[c], __shfl_xor(cminp[c], m, 64));
        cmaxn[c] = fmaxf(cmaxn[c], __shfl_xor(cmaxn[c], m, 64));
      }
    }
    if (quad == 0) {
#pragma unroll
      for (int c = 0; c < 4; ++c) {
        int row = jBase + wc * 64 + c * 16 + n16;
        atomicMin(&minpos_enc[row], enc_f32(cminp[c]));
        atomicMax(&maxneg_enc[row], enc_f32(cmaxn[c]));
      }
    }
  }
}

// ---- kernel 3: loss = mean(relu(maxneg_s - minpos_s + margin)) ----
__global__ __launch_bounds__(256) void finalize_loss(
    const int* __restrict__ minpos_enc, const int* __restrict__ maxneg_enc,
    float* __restrict__ out) {
  const int tid = threadIdx.x;
  const int4* mp4 = (const int4*)minpos_enc;
  const int4* mn4 = (const int4*)maxneg_enc;
  float sum = 0.f;
#pragma unroll
  for (int i = 0; i < 8; ++i) {
    int idx = i * 256 + tid;
    int4 a = mp4[idx];
    int4 b = mn4[idx];
    const int* ap = (const int*)&a;
    const int* bp = (const int*)&b;
#pragma unroll
    for (int v = 0; v < 4; ++v) {
      float loss = dec_f32(bp[v]) - dec_f32(ap[v]) + MARGIN;
      sum += loss > 0.f ? loss : 0.f; // relu(-inf) = 0 matches jnp
    }
  }
#pragma unroll
  for (int m = 1; m < 64; m <<= 1) sum += __shfl_xor(sum, m, 64);
  __shared__ float ws4[4];
  const int lane = tid & 63, wave = tid >> 6;
  if (lane == 0) ws4[wave] = sum;
  __syncthreads();
  if (tid == 0) out[0] = (ws4[0] + ws4[1] + ws4[2] + ws4[3]) * (1.0f / N);
}

extern "C" void kernel_launch(void* const* d_in, const int* in_sizes, int n_in,
                              void* d_out, int out_size, void* d_ws, size_t ws_size,
                              hipStream_t stream) {
  const float* emb = (const float*)d_in[0];
  const int* labels = (const int*)d_in[1];
  float* out = (float*)d_out;

  unsigned char* e8 = (unsigned char*)d_ws; // N*D fp8 = 4 MB
  // keep min/max arrays at the 8 MB offset (proven within ws bounds)
  int* minpos_enc = (int*)((char*)d_ws + (size_t)8 * 1024 * 1024);
  int* maxneg_enc = minpos_enc + N;

  normalize_rows<<<N / 4, 256, 0, stream>>>(emb, e8, minpos_enc, maxneg_enc);
  bh_gemm_sym<<<NPAIR, 256, 0, stream>>>(e8, labels, minpos_enc, maxneg_enc);
  finalize_loss<<<1, 256, 0, stream>>>(minpos_enc, maxneg_enc, out);
}